// Round 1
// baseline (4485.777 us; speedup 1.0000x reference)
//
#include <hip/hip_runtime.h>
#include <math.h>

// Equivariant graph attention (Transformer_79302276153378), MI355X fp32.
// Pipeline: K0 node-transform (dst bilinear precompute) -> K1 edge logits+z
// -> K2 edge values scatter (atomics) -> K3 node output linear.

constexpr int NN = 20000;
constexpr int NE = 320000;
constexpr float INV3      = 0.57735026918962576f;  // 1/sqrt(3)
constexpr float INV_SQRT8 = 0.35355339059327373f;  // 1/sqrt(R_DIM)

__device__ __forceinline__ float gelu_tanh(float p) {
    // jax.nn.gelu(approximate=True): 0.5*p*(1+tanh(0.79788456*(p+0.044715 p^3)))
    // == p * sigmoid(2*y)
    float y = 0.7978845608028654f * (p + 0.044715f * p * p * p);
    return p / (1.0f + __expf(-2.0f * y));
}

// ---------------- K0: per-node transform ----------------
// t[n][v][8] = { s.w_ss0, s.w_ss1, (v.w_vv0)*INV3 (3), (v.w_vv1)*INV3 (3) }
__global__ __launch_bounds__(256) void node_transform_kernel(
    const float* __restrict__ node_f,
    const float* __restrict__ w_ss,   // (2,32,32)
    const float* __restrict__ w_vv,   // (2,32,32)
    float* __restrict__ t)            // (NN,32,8)
{
    __shared__ float lws[2048];
    __shared__ float lwv[2048];
    const int tid = threadIdx.x;
    for (int i = tid; i < 2048; i += 256) { lws[i] = w_ss[i]; lwv[i] = w_vv[i]; }
    __syncthreads();

    const int idx = blockIdx.x * 256 + tid;
    if (idx >= NN * 32) return;
    const int n = idx >> 5, v = idx & 31;
    const float* nf = node_f + (size_t)n * 128;

    float t0 = 0.f, t1 = 0.f;
    float tv00 = 0.f, tv01 = 0.f, tv02 = 0.f;
    float tv10 = 0.f, tv11 = 0.f, tv12 = 0.f;
    #pragma unroll
    for (int u = 0; u < 32; ++u) {
        const float s  = nf[u];
        const float vx = nf[32 + 3*u + 0];
        const float vy = nf[32 + 3*u + 1];
        const float vz = nf[32 + 3*u + 2];
        const float a = lws[u*32 + v];
        const float b = lws[1024 + u*32 + v];
        const float c = lwv[u*32 + v];
        const float d = lwv[1024 + u*32 + v];
        t0 = fmaf(s, a, t0);  t1 = fmaf(s, b, t1);
        tv00 = fmaf(vx, c, tv00); tv01 = fmaf(vy, c, tv01); tv02 = fmaf(vz, c, tv02);
        tv10 = fmaf(vx, d, tv10); tv11 = fmaf(vy, d, tv11); tv12 = fmaf(vz, d, tv12);
    }
    float4* o = (float4*)(t + (size_t)idx * 8);
    o[0] = make_float4(t0, t1, tv00 * INV3, tv01 * INV3);
    o[1] = make_float4(tv02 * INV3, tv10 * INV3, tv11 * INV3, tv12 * INV3);
}

// ---------------- K1/K2: per-edge fused MLP + tensor product ----------------
// PHASE2=false: compute logit, write expw[e], atomic z[dst].
// PHASE2=true : compute coef=sqrt(alpha)/8, scatter edge_v into accN[dst].
template<int BS, bool PHASE2>
__global__ __launch_bounds__(BS) void edge_kernel(
    const int*   __restrict__ esrc,
    const int*   __restrict__ edst,
    const float* __restrict__ xattr,   // (NE,8)
    const float* __restrict__ eattr,   // (NE,4)
    const float* __restrict__ cutoff,  // (NE,)
    const float* __restrict__ node_f,  // (NN,128)
    const float* __restrict__ w1,      // (8,64)
    const float* __restrict__ w2,      // (64,128)
    const float* __restrict__ t,       // (NN,256)  [phase1]
    float* __restrict__ expw,          // (NE,)
    float* __restrict__ z,             // (NN,)
    float* __restrict__ accN)          // (NN,256)  [phase2]
{
    __shared__ float hl[64 * BS];      // h per thread, transposed: hl[j*BS+tid]
    const int tid = threadIdx.x;
    const int e = blockIdx.x * BS + tid;
    if (e >= NE) return;

    // x (8), edge_attr (4)
    const float4* xp = (const float4*)(xattr + (size_t)e * 8);
    const float4 x0 = xp[0], x1 = xp[1];
    float x[8] = {x0.x, x0.y, x0.z, x0.w, x1.x, x1.y, x1.z, x1.w};

    // layer 1: h = gelu((x @ w1) / sqrt(8)); keep per-thread column in LDS
    #pragma unroll
    for (int j = 0; j < 64; ++j) {
        float p = 0.f;
        #pragma unroll
        for (int r = 0; r < 8; ++r) p = fmaf(x[r], w1[r*64 + j], p);
        hl[j*BS + tid] = gelu_tanh(p * INV_SQRT8);
    }

    const int src = esrc[e], dst = edst[e];
    const float* nfs = node_f + (size_t)src * 128;
    const float4 ea = *(const float4*)(eattr + (size_t)e * 4);
    const float a0 = ea.x, a10 = ea.y, a11 = ea.z, a12 = ea.w;

    float scal = 0.f;
    float coef = 0.f;
    const float* td = nullptr;
    float* ad = nullptr;
    if (PHASE2) {
        float zv = z[dst];
        if (zv == 0.f) zv = 1.f;
        coef = sqrtf(expw[e] / zv) * 0.125f;   // sqrt(alpha) * w2-scale(1/8)
        ad = accN + (size_t)dst * 256;
    } else {
        td = t + (size_t)dst * 256;
    }

    // layer 2 dots (8 v at a time) + per-v epilogue
    #pragma unroll
    for (int g = 0; g < 4; ++g) {
        float A0[8] = {0.f}, A1[8] = {0.f}, A2[8] = {0.f}, A3[8] = {0.f};
        for (int i = 0; i < 64; ++i) {                 // rolled: uniform w2 rows
            const float hi = hl[i*BS + tid];
            const float* wr = w2 + i*128 + g*8;
            #pragma unroll
            for (int dv = 0; dv < 8; ++dv) {
                A0[dv] = fmaf(hi, wr[dv],      A0[dv]);
                A1[dv] = fmaf(hi, wr[32 + dv], A1[dv]);
                A2[dv] = fmaf(hi, wr[64 + dv], A2[dv]);
                A3[dv] = fmaf(hi, wr[96 + dv], A3[dv]);
            }
        }
        #pragma unroll
        for (int dv = 0; dv < 8; ++dv) {
            const int v = g*8 + dv;
            const float s  = nfs[v];
            const float vx = nfs[32 + 3*v + 0];
            const float vy = nfs[32 + 3*v + 1];
            const float vz = nfs[32 + 3*v + 2];
            const float sv = vx*a10 + vy*a11 + vz*a12;   // v_src . a1
            if (!PHASE2) {
                const float4 t4a = *(const float4*)(td + v*8);
                const float4 t4b = *(const float4*)(td + v*8 + 4);
                const float d0 = t4a.z*a10 + t4a.w*a11 + t4b.x*a12; // tv0 . a1
                const float d1 = t4b.y*vx + t4b.z*vy + t4b.w*vz;    // tv1 . v_src
                scal += t4a.x * (A0[dv] * s * a0)
                      + t4a.y * (A3[dv] * sv * INV3)
                      + (A1[dv] * s)  * d0
                      + (A2[dv] * a0) * d1;
            } else {
                const float es0 = coef * A0[dv] * s * a0;
                const float es1 = coef * A3[dv] * sv * INV3;
                const float w1s = coef * A1[dv] * s;    // * a1[k]
                const float w2a = coef * A2[dv] * a0;   // * v_src[k]
                unsafeAtomicAdd(ad + v,        es0);
                unsafeAtomicAdd(ad + 32 + v,   es1);
                unsafeAtomicAdd(ad + 64  + 3*v + 0, w1s * a10);
                unsafeAtomicAdd(ad + 64  + 3*v + 1, w1s * a11);
                unsafeAtomicAdd(ad + 64  + 3*v + 2, w1s * a12);
                unsafeAtomicAdd(ad + 160 + 3*v + 0, w2a * vx);
                unsafeAtomicAdd(ad + 160 + 3*v + 1, w2a * vy);
                unsafeAtomicAdd(ad + 160 + 3*v + 2, w2a * vz);
            }
        }
    }

    if (!PHASE2) {
        const float logit = scal * (0.125f / 64.0f);   // w2-scale/8 then /64
        const float ex = cutoff[e] * expf(logit);
        expw[e] = ex;
        unsafeAtomicAdd(&z[dst], ex);
    }
}

// ---------------- K3: final node linears ----------------
__global__ __launch_bounds__(256) void node_out_kernel(
    const float* __restrict__ acc,     // (NN,256)
    const float* __restrict__ lin_ws,  // (64,32)
    const float* __restrict__ lin_wv,  // (64,32)
    float* __restrict__ out)           // (NN,128)
{
    const int idx = blockIdx.x * 256 + threadIdx.x;
    if (idx >= NN * 32) return;
    const int n = idx >> 5, o = idx & 31;
    const float* a = acc + (size_t)n * 256;

    float os = 0.f, ov0 = 0.f, ov1 = 0.f, ov2 = 0.f;
    #pragma unroll
    for (int u = 0; u < 64; ++u) {
        os = fmaf(a[u], lin_ws[u*32 + o], os);
        const float w = lin_wv[u*32 + o];
        ov0 = fmaf(a[64 + 3*u + 0], w, ov0);
        ov1 = fmaf(a[64 + 3*u + 1], w, ov1);
        ov2 = fmaf(a[64 + 3*u + 2], w, ov2);
    }
    float* on = out + (size_t)n * 128;
    on[o]            = os  * 0.125f;
    on[32 + 3*o + 0] = ov0 * 0.125f;
    on[32 + 3*o + 1] = ov1 * 0.125f;
    on[32 + 3*o + 2] = ov2 * 0.125f;
}

extern "C" void kernel_launch(void* const* d_in, const int* in_sizes, int n_in,
                              void* d_out, int out_size, void* d_ws, size_t ws_size,
                              hipStream_t stream) {
    const int*   esrc    = (const int*)  d_in[0];
    const int*   edst    = (const int*)  d_in[1];
    const float* xattr   = (const float*)d_in[2];
    const float* eattr   = (const float*)d_in[3];
    const float* cutoff  = (const float*)d_in[4];
    const float* node_f  = (const float*)d_in[5];
    const float* k_w1    = (const float*)d_in[6];
    const float* k_w2    = (const float*)d_in[7];
    const float* v_w1    = (const float*)d_in[8];
    const float* v_w2    = (const float*)d_in[9];
    const float* w_ss    = (const float*)d_in[10];
    const float* w_vv    = (const float*)d_in[11];
    const float* lin_ws  = (const float*)d_in[12];
    const float* lin_wv  = (const float*)d_in[13];
    float* out = (float*)d_out;

    // workspace layout (floats): t (NN*256) | acc (NN*256) | z (NN) | expw (NE)
    float* t    = (float*)d_ws;
    float* acc  = t + (size_t)NN * 256;
    float* z    = acc + (size_t)NN * 256;
    float* expw = z + NN;

    // zero acc + z (contiguous)
    hipMemsetAsync(acc, 0, ((size_t)NN * 256 + NN) * sizeof(float), stream);

    node_transform_kernel<<<(NN*32 + 255)/256, 256, 0, stream>>>(node_f, w_ss, w_vv, t);

    constexpr int BS = 128;
    edge_kernel<BS, false><<<(NE + BS - 1)/BS, BS, 0, stream>>>(
        esrc, edst, xattr, eattr, cutoff, node_f, k_w1, k_w2, t, expw, z, acc);
    edge_kernel<BS, true><<<(NE + BS - 1)/BS, BS, 0, stream>>>(
        esrc, edst, xattr, eattr, cutoff, node_f, v_w1, v_w2, t, expw, z, acc);

    node_out_kernel<<<(NN*32 + 255)/256, 256, 0, stream>>>(acc, lin_ws, lin_wv, out);
}

// Round 2
// 900.601 us; speedup vs baseline: 4.9809x; 4.9809x over previous
//
#include <hip/hip_runtime.h>
#include <math.h>

// Equivariant graph attention (Transformer_79302276153378), MI355X fp32.
// Round 2: kill the 82M fp32 atomics. CSR-by-dst (hist/scan/scatter) +
// column-parallel edge kernels (thread j owns w2 column j in registers).
//
// Pipeline: memset(z,cnt) -> K0 node-transform -> hist -> scan -> scatter
//           -> logit (edge tiles, shfl-reduce, expw+z) -> value (block-per-node
//           reduce, no atomics) -> K3 node linears.

constexpr int NN = 20000;
constexpr int NE = 320000;
constexpr float INV3      = 0.57735026918962576f;  // 1/sqrt(3)
constexpr float INV_SQRT8 = 0.35355339059327373f;  // 1/sqrt(R_DIM)

__device__ __forceinline__ float gelu_tanh(float p) {
    // jax.nn.gelu(approximate=True) == p * sigmoid(2*0.79788456*(p+0.044715p^3))
    float y = 0.7978845608028654f * (p + 0.044715f * p * p * p);
    return p / (1.0f + __expf(-2.0f * y));
}

// ---------------- K0: per-node dst transform ----------------
// t[n][v][8] = { s.w_ss0, s.w_ss1, (v.w_vv0)*INV3 (3), (v.w_vv1)*INV3 (3) }
__global__ __launch_bounds__(256) void node_transform_kernel(
    const float* __restrict__ node_f,
    const float* __restrict__ w_ss,   // (2,32,32)
    const float* __restrict__ w_vv,   // (2,32,32)
    float* __restrict__ t)            // (NN,32,8)
{
    __shared__ float lws[2048];
    __shared__ float lwv[2048];
    const int tid = threadIdx.x;
    for (int i = tid; i < 2048; i += 256) { lws[i] = w_ss[i]; lwv[i] = w_vv[i]; }
    __syncthreads();

    const int idx = blockIdx.x * 256 + tid;
    if (idx >= NN * 32) return;
    const int n = idx >> 5, v = idx & 31;
    const float* nf = node_f + (size_t)n * 128;

    float t0 = 0.f, t1 = 0.f;
    float tv00 = 0.f, tv01 = 0.f, tv02 = 0.f;
    float tv10 = 0.f, tv11 = 0.f, tv12 = 0.f;
    #pragma unroll
    for (int u = 0; u < 32; ++u) {
        const float s  = nf[u];
        const float vx = nf[32 + 3*u + 0];
        const float vy = nf[32 + 3*u + 1];
        const float vz = nf[32 + 3*u + 2];
        const float a = lws[u*32 + v];
        const float b = lws[1024 + u*32 + v];
        const float c = lwv[u*32 + v];
        const float d = lwv[1024 + u*32 + v];
        t0 = fmaf(s, a, t0);  t1 = fmaf(s, b, t1);
        tv00 = fmaf(vx, c, tv00); tv01 = fmaf(vy, c, tv01); tv02 = fmaf(vz, c, tv02);
        tv10 = fmaf(vx, d, tv10); tv11 = fmaf(vy, d, tv11); tv12 = fmaf(vz, d, tv12);
    }
    float4* o = (float4*)(t + (size_t)idx * 8);
    o[0] = make_float4(t0, t1, tv00 * INV3, tv01 * INV3);
    o[1] = make_float4(tv02 * INV3, tv10 * INV3, tv11 * INV3, tv12 * INV3);
}

// ---------------- CSR build ----------------
__global__ __launch_bounds__(256) void hist_kernel(
    const int* __restrict__ edst, int* __restrict__ cnt)
{
    const int e = blockIdx.x * 256 + threadIdx.x;
    if (e < NE) atomicAdd(&cnt[edst[e]], 1);
}

__global__ __launch_bounds__(256) void scan_kernel(
    const int* __restrict__ cnt, int* __restrict__ rowptr, int* __restrict__ woff)
{
    __shared__ int buf[256];
    __shared__ int carry_s;
    if (threadIdx.x == 0) carry_s = 0;
    __syncthreads();
    for (int base = 0; base < NN; base += 256) {
        const int i = base + threadIdx.x;
        const int vv = (i < NN) ? cnt[i] : 0;
        buf[threadIdx.x] = vv;
        __syncthreads();
        #pragma unroll
        for (int off = 1; off < 256; off <<= 1) {
            const int tc = (threadIdx.x >= off) ? buf[threadIdx.x - off] : 0;
            __syncthreads();
            buf[threadIdx.x] += tc;
            __syncthreads();
        }
        const int excl = buf[threadIdx.x] - vv + carry_s;   // exclusive prefix
        if (i < NN) { rowptr[i] = excl; woff[i] = excl; }
        __syncthreads();
        if (threadIdx.x == 255) carry_s += buf[255];
        __syncthreads();
    }
    if (threadIdx.x == 0) rowptr[NN] = carry_s;             // == NE
}

__global__ __launch_bounds__(256) void scatter_kernel(
    const int* __restrict__ edst, int* __restrict__ woff, int* __restrict__ perm)
{
    const int e = blockIdx.x * 256 + threadIdx.x;
    if (e < NE) {
        const int pos = atomicAdd(&woff[edst[e]], 1);
        perm[pos] = e;
    }
}

// ---------------- Phase 1: logits (column-parallel, 64 edges / block) ----------
template<int ET>
__global__ __launch_bounds__(128) void logit_kernel(
    const int*   __restrict__ esrc,
    const int*   __restrict__ edst,
    const float* __restrict__ xattr,   // (NE,8)
    const float* __restrict__ eattr,   // (NE,4)
    const float* __restrict__ cutoff,  // (NE,)
    const float* __restrict__ node_f,  // (NN,128)
    const float* __restrict__ w1,      // (8,64)
    const float* __restrict__ w2,      // (64,128)
    const float* __restrict__ t,       // (NN,32,8)
    float* __restrict__ expw,          // (NE,)
    float* __restrict__ z)             // (NN,)
{
    __shared__ float nf[128];
    __shared__ float tt[32 * 9];       // padded: bank-conflict-free tv reads
    __shared__ float4 h4[16];
    __shared__ float xs[8];
    __shared__ float eas[4];
    __shared__ float cut_s;
    __shared__ float part[2];

    const int tid = threadIdx.x;
    const int v = tid & 31, grp = tid >> 5;

    float w2c[64];
    #pragma unroll
    for (int i = 0; i < 64; ++i) w2c[i] = w2[i*128 + tid];   // coalesced per i
    float w1c[8] = {};
    if (tid < 64) {
        #pragma unroll
        for (int r = 0; r < 8; ++r) w1c[r] = w1[r*64 + tid];
    }

    const int e0 = blockIdx.x * ET;
    for (int et = 0; et < ET; ++et) {
        const int e = e0 + et;
        const int src = esrc[e], dst = edst[e];
        nf[tid] = node_f[(size_t)src * 128 + tid];
        {
            const int i0 = tid, i1 = tid + 128;
            tt[(i0 >> 3) * 9 + (i0 & 7)] = t[(size_t)dst * 256 + i0];
            tt[(i1 >> 3) * 9 + (i1 & 7)] = t[(size_t)dst * 256 + i1];
        }
        if (tid < 8)                 xs[tid]      = xattr[(size_t)e*8 + tid];
        else if (tid < 12)           eas[tid - 8] = eattr[(size_t)e*4 + tid - 8];
        else if (tid == 12)          cut_s        = cutoff[e];
        __syncthreads();

        if (tid < 64) {
            float p = 0.f;
            #pragma unroll
            for (int r = 0; r < 8; ++r) p = fmaf(xs[r], w1c[r], p);
            ((float*)h4)[tid] = gelu_tanh(p * INV_SQRT8);
        }
        __syncthreads();

        float A = 0.f;
        #pragma unroll
        for (int i4 = 0; i4 < 16; ++i4) {
            const float4 hh = h4[i4];
            A = fmaf(hh.x, w2c[4*i4+0], A);
            A = fmaf(hh.y, w2c[4*i4+1], A);
            A = fmaf(hh.z, w2c[4*i4+2], A);
            A = fmaf(hh.w, w2c[4*i4+3], A);
        }

        const float a0 = eas[0], a10 = eas[1], a11 = eas[2], a12 = eas[3];
        const float s_v = nf[v];
        const float vx = nf[32 + 3*v], vy = nf[33 + 3*v], vz = nf[34 + 3*v];
        const float* tv = tt + v * 9;
        float c;
        if (grp == 0)      c = tv[0] * A * s_v * a0;
        else if (grp == 1) c = A * s_v * (tv[2]*a10 + tv[3]*a11 + tv[4]*a12);
        else if (grp == 2) c = A * a0  * (tv[5]*vx  + tv[6]*vy  + tv[7]*vz);
        else               c = tv[1] * A * (vx*a10 + vy*a11 + vz*a12) * INV3;

        #pragma unroll
        for (int m = 1; m < 64; m <<= 1) c += __shfl_xor(c, m, 64);
        if ((tid & 63) == 0) part[tid >> 6] = c;
        __syncthreads();
        if (tid == 0) {
            const float logit = (part[0] + part[1]) * (0.125f / 64.0f);
            const float ex = cut_s * expf(logit);
            expw[e] = ex;
            unsafeAtomicAdd(&z[dst], ex);
        }
        __syncthreads();
    }
}

// ---------------- Phase 2: value reduce (one block per node, no atomics) ------
__global__ __launch_bounds__(128) void value_kernel(
    const int*   __restrict__ rowptr,
    const int*   __restrict__ perm,
    const int*   __restrict__ esrc,
    const float* __restrict__ xattr,
    const float* __restrict__ eattr,
    const float* __restrict__ node_f,
    const float* __restrict__ w1,
    const float* __restrict__ w2,
    const float* __restrict__ expw,
    const float* __restrict__ z,
    float* __restrict__ acc)           // (NN,256)
{
    __shared__ float nf[128];
    __shared__ float4 h4[16];
    __shared__ float xs[8];
    __shared__ float eas[4];
    __shared__ float ew_s;

    const int n = blockIdx.x;
    const int tid = threadIdx.x;
    const int v = tid & 31, grp = tid >> 5;

    float w2c[64];
    #pragma unroll
    for (int i = 0; i < 64; ++i) w2c[i] = w2[i*128 + tid];
    float w1c[8] = {};
    if (tid < 64) {
        #pragma unroll
        for (int r = 0; r < 8; ++r) w1c[r] = w1[r*64 + tid];
    }

    float zv = z[n];
    if (zv == 0.f) zv = 1.f;
    const float inv_z = 1.0f / zv;
    const int k0 = rowptr[n], k1 = rowptr[n + 1];

    float ac0 = 0.f, ac1 = 0.f, ac2 = 0.f;

    for (int k = k0; k < k1; ++k) {
        const int e = perm[k];
        const int src = esrc[e];
        nf[tid] = node_f[(size_t)src * 128 + tid];
        if (tid < 8)        xs[tid]      = xattr[(size_t)e*8 + tid];
        else if (tid < 12)  eas[tid - 8] = eattr[(size_t)e*4 + tid - 8];
        else if (tid == 12) ew_s         = expw[e];
        __syncthreads();

        if (tid < 64) {
            float p = 0.f;
            #pragma unroll
            for (int r = 0; r < 8; ++r) p = fmaf(xs[r], w1c[r], p);
            ((float*)h4)[tid] = gelu_tanh(p * INV_SQRT8);
        }
        __syncthreads();

        float A = 0.f;
        #pragma unroll
        for (int i4 = 0; i4 < 16; ++i4) {
            const float4 hh = h4[i4];
            A = fmaf(hh.x, w2c[4*i4+0], A);
            A = fmaf(hh.y, w2c[4*i4+1], A);
            A = fmaf(hh.z, w2c[4*i4+2], A);
            A = fmaf(hh.w, w2c[4*i4+3], A);
        }

        const float coef = sqrtf(ew_s * inv_z) * 0.125f;  // sqrt(alpha)*w2scale
        const float a0 = eas[0], a10 = eas[1], a11 = eas[2], a12 = eas[3];
        const float s_v = nf[v];
        const float vx = nf[32 + 3*v], vy = nf[33 + 3*v], vz = nf[34 + 3*v];
        const float cA = coef * A;
        if (grp == 0) {
            ac0 = fmaf(cA, s_v * a0, ac0);
        } else if (grp == 1) {
            const float tq = cA * s_v;
            ac0 = fmaf(tq, a10, ac0); ac1 = fmaf(tq, a11, ac1); ac2 = fmaf(tq, a12, ac2);
        } else if (grp == 2) {
            const float tq = cA * a0;
            ac0 = fmaf(tq, vx, ac0);  ac1 = fmaf(tq, vy, ac1);  ac2 = fmaf(tq, vz, ac2);
        } else {
            ac0 = fmaf(cA * INV3, vx*a10 + vy*a11 + vz*a12, ac0);
        }
        __syncthreads();
    }

    float* ad = acc + (size_t)n * 256;
    if (grp == 0)      { ad[v] = ac0; }
    else if (grp == 3) { ad[32 + v] = ac0; }
    else if (grp == 1) { ad[64  + 3*v] = ac0; ad[65  + 3*v] = ac1; ad[66  + 3*v] = ac2; }
    else               { ad[160 + 3*v] = ac0; ad[161 + 3*v] = ac1; ad[162 + 3*v] = ac2; }
}

// ---------------- K3: final node linears ----------------
__global__ __launch_bounds__(256) void node_out_kernel(
    const float* __restrict__ acc,     // (NN,256)
    const float* __restrict__ lin_ws,  // (64,32)
    const float* __restrict__ lin_wv,  // (64,32)
    float* __restrict__ out)           // (NN,128)
{
    const int idx = blockIdx.x * 256 + threadIdx.x;
    if (idx >= NN * 32) return;
    const int n = idx >> 5, o = idx & 31;
    const float* a = acc + (size_t)n * 256;

    float os = 0.f, ov0 = 0.f, ov1 = 0.f, ov2 = 0.f;
    #pragma unroll
    for (int u = 0; u < 64; ++u) {
        os = fmaf(a[u], lin_ws[u*32 + o], os);
        const float w = lin_wv[u*32 + o];
        ov0 = fmaf(a[64 + 3*u + 0], w, ov0);
        ov1 = fmaf(a[64 + 3*u + 1], w, ov1);
        ov2 = fmaf(a[64 + 3*u + 2], w, ov2);
    }
    float* on = out + (size_t)n * 128;
    on[o]            = os  * 0.125f;
    on[32 + 3*o + 0] = ov0 * 0.125f;
    on[32 + 3*o + 1] = ov1 * 0.125f;
    on[32 + 3*o + 2] = ov2 * 0.125f;
}

extern "C" void kernel_launch(void* const* d_in, const int* in_sizes, int n_in,
                              void* d_out, int out_size, void* d_ws, size_t ws_size,
                              hipStream_t stream) {
    const int*   esrc    = (const int*)  d_in[0];
    const int*   edst    = (const int*)  d_in[1];
    const float* xattr   = (const float*)d_in[2];
    const float* eattr   = (const float*)d_in[3];
    const float* cutoff  = (const float*)d_in[4];
    const float* node_f  = (const float*)d_in[5];
    const float* k_w1    = (const float*)d_in[6];
    const float* k_w2    = (const float*)d_in[7];
    const float* v_w1    = (const float*)d_in[8];
    const float* v_w2    = (const float*)d_in[9];
    const float* w_ss    = (const float*)d_in[10];
    const float* w_vv    = (const float*)d_in[11];
    const float* lin_ws  = (const float*)d_in[12];
    const float* lin_wv  = (const float*)d_in[13];
    float* out = (float*)d_out;

    // workspace: floats [t NN*256 | acc NN*256 | z NN | expw NE] then
    //            ints   [cnt NN | rowptr NN+1 | woff NN | perm NE]   (~44 MB)
    float* t    = (float*)d_ws;
    float* acc  = t + (size_t)NN * 256;
    float* z    = acc + (size_t)NN * 256;
    float* expw = z + NN;
    int*   cnt    = (int*)(expw + NE);
    int*   rowptr = cnt + NN;
    int*   woff   = rowptr + NN + 1;
    int*   perm   = woff + NN;

    hipMemsetAsync(z, 0, NN * sizeof(float), stream);
    hipMemsetAsync(cnt, 0, NN * sizeof(int), stream);

    node_transform_kernel<<<(NN*32 + 255)/256, 256, 0, stream>>>(node_f, w_ss, w_vv, t);

    hist_kernel<<<(NE + 255)/256, 256, 0, stream>>>(edst, cnt);
    scan_kernel<<<1, 256, 0, stream>>>(cnt, rowptr, woff);
    scatter_kernel<<<(NE + 255)/256, 256, 0, stream>>>(edst, woff, perm);

    logit_kernel<64><<<NE/64, 128, 0, stream>>>(
        esrc, edst, xattr, eattr, cutoff, node_f, k_w1, k_w2, t, expw, z);

    value_kernel<<<NN, 128, 0, stream>>>(
        rowptr, perm, esrc, xattr, eattr, node_f, v_w1, v_w2, expw, z, acc);

    node_out_kernel<<<(NN*32 + 255)/256, 256, 0, stream>>>(acc, lin_ws, lin_wv, out);
}

// Round 3
// 715.352 us; speedup vs baseline: 6.2707x; 1.2590x over previous
//
#include <hip/hip_runtime.h>
#include <math.h>

// Equivariant graph attention (Transformer_79302276153378), MI355X fp32.
// Round 3: both edge phases block-per-node over CSR, 8-edge tiles,
// col-stationary w2 in VGPRs (launch_bounds(128,4) so it actually stays
// resident), h broadcast from LDS, t[dst] staged once per block, z local.

constexpr int NN = 20000;
constexpr int NE = 320000;
constexpr int TE = 8;                              // edges per tile
constexpr float INV3      = 0.57735026918962576f;  // 1/sqrt(3)
constexpr float INV_SQRT8 = 0.35355339059327373f;  // 1/sqrt(R_DIM)

__device__ __forceinline__ float gelu_tanh(float p) {
    // jax.nn.gelu(approximate=True) == p * sigmoid(2*0.79788456*(p+0.044715p^3))
    float y = 0.7978845608028654f * (p + 0.044715f * p * p * p);
    return p / (1.0f + __expf(-2.0f * y));
}

// ---------------- K0: per-node dst transform ----------------
// t[n][v][8] = { s.w_ss0, s.w_ss1, (v.w_vv0)*INV3 (3), (v.w_vv1)*INV3 (3) }
__global__ __launch_bounds__(256) void node_transform_kernel(
    const float* __restrict__ node_f,
    const float* __restrict__ w_ss,   // (2,32,32)
    const float* __restrict__ w_vv,   // (2,32,32)
    float* __restrict__ t)            // (NN,32,8)
{
    __shared__ float lws[2048];
    __shared__ float lwv[2048];
    const int tid = threadIdx.x;
    for (int i = tid; i < 2048; i += 256) { lws[i] = w_ss[i]; lwv[i] = w_vv[i]; }
    __syncthreads();

    const int idx = blockIdx.x * 256 + tid;
    if (idx >= NN * 32) return;
    const int n = idx >> 5, v = idx & 31;
    const float* nf = node_f + (size_t)n * 128;

    float t0 = 0.f, t1 = 0.f;
    float tv00 = 0.f, tv01 = 0.f, tv02 = 0.f;
    float tv10 = 0.f, tv11 = 0.f, tv12 = 0.f;
    #pragma unroll
    for (int u = 0; u < 32; ++u) {
        const float s  = nf[u];
        const float vx = nf[32 + 3*u + 0];
        const float vy = nf[32 + 3*u + 1];
        const float vz = nf[32 + 3*u + 2];
        const float a = lws[u*32 + v];
        const float b = lws[1024 + u*32 + v];
        const float c = lwv[u*32 + v];
        const float d = lwv[1024 + u*32 + v];
        t0 = fmaf(s, a, t0);  t1 = fmaf(s, b, t1);
        tv00 = fmaf(vx, c, tv00); tv01 = fmaf(vy, c, tv01); tv02 = fmaf(vz, c, tv02);
        tv10 = fmaf(vx, d, tv10); tv11 = fmaf(vy, d, tv11); tv12 = fmaf(vz, d, tv12);
    }
    float4* o = (float4*)(t + (size_t)idx * 8);
    o[0] = make_float4(t0, t1, tv00 * INV3, tv01 * INV3);
    o[1] = make_float4(tv02 * INV3, tv10 * INV3, tv11 * INV3, tv12 * INV3);
}

// ---------------- CSR build ----------------
__global__ __launch_bounds__(256) void hist_kernel(
    const int* __restrict__ edst, int* __restrict__ cnt)
{
    const int e = blockIdx.x * 256 + threadIdx.x;
    if (e < NE) atomicAdd(&cnt[edst[e]], 1);
}

__global__ __launch_bounds__(256) void scan_kernel(
    const int* __restrict__ cnt, int* __restrict__ rowptr, int* __restrict__ woff)
{
    __shared__ int buf[256];
    __shared__ int carry_s;
    if (threadIdx.x == 0) carry_s = 0;
    __syncthreads();
    for (int base = 0; base < NN; base += 256) {
        const int i = base + threadIdx.x;
        const int vv = (i < NN) ? cnt[i] : 0;
        buf[threadIdx.x] = vv;
        __syncthreads();
        #pragma unroll
        for (int off = 1; off < 256; off <<= 1) {
            const int tc = (threadIdx.x >= off) ? buf[threadIdx.x - off] : 0;
            __syncthreads();
            buf[threadIdx.x] += tc;
            __syncthreads();
        }
        const int excl = buf[threadIdx.x] - vv + carry_s;   // exclusive prefix
        if (i < NN) { rowptr[i] = excl; woff[i] = excl; }
        __syncthreads();
        if (threadIdx.x == 255) carry_s += buf[255];
        __syncthreads();
    }
    if (threadIdx.x == 0) rowptr[NN] = carry_s;             // == NE
}

__global__ __launch_bounds__(256) void scatter_kernel(
    const int* __restrict__ edst, int* __restrict__ woff, int* __restrict__ perm)
{
    const int e = blockIdx.x * 256 + threadIdx.x;
    if (e < NE) {
        const int pos = atomicAdd(&woff[edst[e]], 1);
        perm[pos] = e;
    }
}

// ---------------- Phase 1: logits, block-per-node, 8-edge tiles --------------
__global__ __launch_bounds__(128, 4) void logit_kernel(
    const int*   __restrict__ rowptr,
    const int*   __restrict__ perm,
    const int*   __restrict__ esrc,
    const float* __restrict__ xattr,   // (NE,8)
    const float* __restrict__ eattr,   // (NE,4)
    const float* __restrict__ cutoff,  // (NE,)
    const float* __restrict__ node_f,  // (NN,128)
    const float* __restrict__ w1,      // (8,64)
    const float* __restrict__ w2,      // (64,128)
    const float* __restrict__ t,       // (NN,32,8)
    float* __restrict__ expw,          // (NE,) CSR order
    float* __restrict__ z)             // (NN,)
{
    __shared__ float nf[TE][128];
    __shared__ float tt[32 * 9];
    __shared__ float h[TE][64];
    __shared__ float xs[TE][8];
    __shared__ float eas[TE][4];
    __shared__ float cut[TE];
    __shared__ int   eid[TE];
    __shared__ int   srcid[TE];
    __shared__ float part[2][TE];

    const int n = blockIdx.x;
    const int tid = threadIdx.x;
    const int v = tid & 31, grp = tid >> 5;

    float w2c[64];
    #pragma unroll
    for (int i = 0; i < 64; ++i) w2c[i] = w2[i*128 + tid];   // coalesced per i
    float w1c[8];
    #pragma unroll
    for (int r = 0; r < 8; ++r) w1c[r] = w1[r*64 + (tid & 63)];

    // stage t[n] once, padded (bank-conflict-free)
    {
        const int i0 = tid, i1 = tid + 128;
        tt[(i0 >> 3) * 9 + (i0 & 7)] = t[(size_t)n * 256 + i0];
        tt[(i1 >> 3) * 9 + (i1 & 7)] = t[(size_t)n * 256 + i1];
    }

    const int k0 = rowptr[n], k1 = rowptr[n + 1];
    float zacc = 0.f;   // lanes tid<TE accumulate their edge-slot's exp

    for (int kb = k0; kb < k1; kb += TE) {
        const int nt = min(TE, k1 - kb);
        __syncthreads();                       // WAR: prev tile fully consumed
        if (tid < nt) {
            const int e = perm[kb + tid];
            eid[tid] = e; srcid[tid] = esrc[e]; cut[tid] = cutoff[e];
        }
        __syncthreads();
        for (int j = 0; j < nt; ++j)
            nf[j][tid] = node_f[(size_t)srcid[j] * 128 + tid];
        if (tid < nt * 8) xs[tid >> 3][tid & 7] = xattr[(size_t)eid[tid >> 3]*8 + (tid & 7)];
        if (tid < nt * 4) eas[tid >> 2][tid & 3] = eattr[(size_t)eid[tid >> 2]*4 + (tid & 3)];
        __syncthreads();
        #pragma unroll
        for (int r = 0; r < 4; ++r) {
            const int idx = tid + 128 * r;
            const int j = idx >> 6;
            if (j < nt) {
                float p = 0.f;
                #pragma unroll
                for (int rr = 0; rr < 8; ++rr) p = fmaf(xs[j][rr], w1c[rr], p);
                h[j][tid & 63] = gelu_tanh(p * INV_SQRT8);
            }
        }
        __syncthreads();

        for (int j = 0; j < nt; ++j) {
            const float4* h4 = (const float4*)h[j];
            float A = 0.f;
            #pragma unroll
            for (int i4 = 0; i4 < 16; ++i4) {
                const float4 hh = h4[i4];
                A = fmaf(hh.x, w2c[4*i4+0], A);
                A = fmaf(hh.y, w2c[4*i4+1], A);
                A = fmaf(hh.z, w2c[4*i4+2], A);
                A = fmaf(hh.w, w2c[4*i4+3], A);
            }
            const float a0 = eas[j][0], a10 = eas[j][1], a11 = eas[j][2], a12 = eas[j][3];
            const float s_v = nf[j][v];
            const float vx = nf[j][32 + 3*v], vy = nf[j][33 + 3*v], vz = nf[j][34 + 3*v];
            const float* tv = tt + v * 9;
            float c;
            if (grp == 0)      c = tv[0] * A * s_v * a0;
            else if (grp == 1) c = A * s_v * (tv[2]*a10 + tv[3]*a11 + tv[4]*a12);
            else if (grp == 2) c = A * a0  * (tv[5]*vx  + tv[6]*vy  + tv[7]*vz);
            else               c = tv[1] * A * (vx*a10 + vy*a11 + vz*a12) * INV3;
            #pragma unroll
            for (int m = 1; m < 64; m <<= 1) c += __shfl_xor(c, m, 64);
            if ((tid & 63) == 0) part[tid >> 6][j] = c;
        }
        __syncthreads();
        if (tid < nt) {
            const float logit = (part[0][tid] + part[1][tid]) * (0.125f / 64.0f);
            const float ex = cut[tid] * expf(logit);
            expw[kb + tid] = ex;
            zacc += ex;
        }
    }

    // reduce zacc over lanes 0..TE-1 of wave 0 and store
    if (tid < TE) {
        #pragma unroll
        for (int m = TE >> 1; m >= 1; m >>= 1) zacc += __shfl_xor(zacc, m, 64);
        if (tid == 0) z[n] = zacc;
    }
}

// ---------------- Phase 2: values, block-per-node, 8-edge tiles --------------
__global__ __launch_bounds__(128, 4) void value_kernel(
    const int*   __restrict__ rowptr,
    const int*   __restrict__ perm,
    const int*   __restrict__ esrc,
    const float* __restrict__ xattr,
    const float* __restrict__ eattr,
    const float* __restrict__ node_f,
    const float* __restrict__ w1,
    const float* __restrict__ w2,
    const float* __restrict__ expw,    // (NE,) CSR order
    const float* __restrict__ z,
    float* __restrict__ acc)           // (NN,256)
{
    __shared__ float nf[TE][128];
    __shared__ float h[TE][64];
    __shared__ float xs[TE][8];
    __shared__ float eas[TE][4];
    __shared__ float cf[TE];
    __shared__ int   eid[TE];
    __shared__ int   srcid[TE];

    const int n = blockIdx.x;
    const int tid = threadIdx.x;
    const int v = tid & 31, grp = tid >> 5;

    float w2c[64];
    #pragma unroll
    for (int i = 0; i < 64; ++i) w2c[i] = w2[i*128 + tid];
    float w1c[8];
    #pragma unroll
    for (int r = 0; r < 8; ++r) w1c[r] = w1[r*64 + (tid & 63)];

    float zv = z[n];
    if (zv == 0.f) zv = 1.f;
    const float inv_z = 1.0f / zv;
    const int k0 = rowptr[n], k1 = rowptr[n + 1];

    float ac0 = 0.f, ac1 = 0.f, ac2 = 0.f;

    for (int kb = k0; kb < k1; kb += TE) {
        const int nt = min(TE, k1 - kb);
        __syncthreads();
        if (tid < nt) {
            const int e = perm[kb + tid];
            eid[tid] = e; srcid[tid] = esrc[e];
            cf[tid] = sqrtf(expw[kb + tid] * inv_z) * 0.125f;  // sqrt(alpha)/8
        }
        __syncthreads();
        for (int j = 0; j < nt; ++j)
            nf[j][tid] = node_f[(size_t)srcid[j] * 128 + tid];
        if (tid < nt * 8) xs[tid >> 3][tid & 7] = xattr[(size_t)eid[tid >> 3]*8 + (tid & 7)];
        if (tid < nt * 4) eas[tid >> 2][tid & 3] = eattr[(size_t)eid[tid >> 2]*4 + (tid & 3)];
        __syncthreads();
        #pragma unroll
        for (int r = 0; r < 4; ++r) {
            const int idx = tid + 128 * r;
            const int j = idx >> 6;
            if (j < nt) {
                float p = 0.f;
                #pragma unroll
                for (int rr = 0; rr < 8; ++rr) p = fmaf(xs[j][rr], w1c[rr], p);
                h[j][tid & 63] = gelu_tanh(p * INV_SQRT8);
            }
        }
        __syncthreads();

        for (int j = 0; j < nt; ++j) {
            const float4* h4 = (const float4*)h[j];
            float A = 0.f;
            #pragma unroll
            for (int i4 = 0; i4 < 16; ++i4) {
                const float4 hh = h4[i4];
                A = fmaf(hh.x, w2c[4*i4+0], A);
                A = fmaf(hh.y, w2c[4*i4+1], A);
                A = fmaf(hh.z, w2c[4*i4+2], A);
                A = fmaf(hh.w, w2c[4*i4+3], A);
            }
            const float a0 = eas[j][0], a10 = eas[j][1], a11 = eas[j][2], a12 = eas[j][3];
            const float s_v = nf[j][v];
            const float vx = nf[j][32 + 3*v], vy = nf[j][33 + 3*v], vz = nf[j][34 + 3*v];
            const float cA = cf[j] * A;
            if (grp == 0) {
                ac0 = fmaf(cA, s_v * a0, ac0);
            } else if (grp == 1) {
                const float tq = cA * s_v;
                ac0 = fmaf(tq, a10, ac0); ac1 = fmaf(tq, a11, ac1); ac2 = fmaf(tq, a12, ac2);
            } else if (grp == 2) {
                const float tq = cA * a0;
                ac0 = fmaf(tq, vx, ac0);  ac1 = fmaf(tq, vy, ac1);  ac2 = fmaf(tq, vz, ac2);
            } else {
                ac0 = fmaf(cA * INV3, vx*a10 + vy*a11 + vz*a12, ac0);
            }
        }
    }

    float* ad = acc + (size_t)n * 256;
    if (grp == 0)      { ad[v] = ac0; }
    else if (grp == 3) { ad[32 + v] = ac0; }
    else if (grp == 1) { ad[64  + 3*v] = ac0; ad[65  + 3*v] = ac1; ad[66  + 3*v] = ac2; }
    else               { ad[160 + 3*v] = ac0; ad[161 + 3*v] = ac1; ad[162 + 3*v] = ac2; }
}

// ---------------- K3: final node linears ----------------
__global__ __launch_bounds__(256) void node_out_kernel(
    const float* __restrict__ acc,     // (NN,256)
    const float* __restrict__ lin_ws,  // (64,32)
    const float* __restrict__ lin_wv,  // (64,32)
    float* __restrict__ out)           // (NN,128)
{
    const int idx = blockIdx.x * 256 + threadIdx.x;
    if (idx >= NN * 32) return;
    const int n = idx >> 5, o = idx & 31;
    const float* a = acc + (size_t)n * 256;

    float os = 0.f, ov0 = 0.f, ov1 = 0.f, ov2 = 0.f;
    #pragma unroll
    for (int u = 0; u < 64; ++u) {
        os = fmaf(a[u], lin_ws[u*32 + o], os);
        const float w = lin_wv[u*32 + o];
        ov0 = fmaf(a[64 + 3*u + 0], w, ov0);
        ov1 = fmaf(a[64 + 3*u + 1], w, ov1);
        ov2 = fmaf(a[64 + 3*u + 2], w, ov2);
    }
    float* on = out + (size_t)n * 128;
    on[o]            = os  * 0.125f;
    on[32 + 3*o + 0] = ov0 * 0.125f;
    on[32 + 3*o + 1] = ov1 * 0.125f;
    on[32 + 3*o + 2] = ov2 * 0.125f;
}

extern "C" void kernel_launch(void* const* d_in, const int* in_sizes, int n_in,
                              void* d_out, int out_size, void* d_ws, size_t ws_size,
                              hipStream_t stream) {
    const int*   esrc    = (const int*)  d_in[0];
    const int*   edst    = (const int*)  d_in[1];
    const float* xattr   = (const float*)d_in[2];
    const float* eattr   = (const float*)d_in[3];
    const float* cutoff  = (const float*)d_in[4];
    const float* node_f  = (const float*)d_in[5];
    const float* k_w1    = (const float*)d_in[6];
    const float* k_w2    = (const float*)d_in[7];
    const float* v_w1    = (const float*)d_in[8];
    const float* v_w2    = (const float*)d_in[9];
    const float* w_ss    = (const float*)d_in[10];
    const float* w_vv    = (const float*)d_in[11];
    const float* lin_ws  = (const float*)d_in[12];
    const float* lin_wv  = (const float*)d_in[13];
    float* out = (float*)d_out;

    // workspace: floats [t NN*256 | acc NN*256 | z NN | expw NE] then
    //            ints   [cnt NN | rowptr NN+1 | woff NN | perm NE]
    float* t    = (float*)d_ws;
    float* acc  = t + (size_t)NN * 256;
    float* z    = acc + (size_t)NN * 256;
    float* expw = z + NN;
    int*   cnt    = (int*)(expw + NE);
    int*   rowptr = cnt + NN;
    int*   woff   = rowptr + NN + 1;
    int*   perm   = woff + NN;

    hipMemsetAsync(cnt, 0, NN * sizeof(int), stream);

    node_transform_kernel<<<(NN*32 + 255)/256, 256, 0, stream>>>(node_f, w_ss, w_vv, t);

    hist_kernel<<<(NE + 255)/256, 256, 0, stream>>>(edst, cnt);
    scan_kernel<<<1, 256, 0, stream>>>(cnt, rowptr, woff);
    scatter_kernel<<<(NE + 255)/256, 256, 0, stream>>>(edst, woff, perm);

    logit_kernel<<<NN, 128, 0, stream>>>(
        rowptr, perm, esrc, xattr, eattr, cutoff, node_f, k_w1, k_w2, t, expw, z);

    value_kernel<<<NN, 128, 0, stream>>>(
        rowptr, perm, esrc, xattr, eattr, node_f, v_w1, v_w2, expw, z, acc);

    node_out_kernel<<<(NN*32 + 255)/256, 256, 0, stream>>>(acc, lin_ws, lin_wv, out);
}